// Round 7
// baseline (509.579 us; speedup 1.0000x reference)
//
#include <hip/hip_runtime.h>

// CapsuleLayer dynamic routing — two-phase, fp32-exact.
//   P[k,b,r,o] = sum_c x[b,r,c] * w[k,r,c,o]   (K=B=32, R=2048, C=16, O=32)
//   u0 = sigmoid(colsum(P)/R); f(v) = P^T softmax(P v)
//   u1 = sigmoid(f(u0)); out = sigmoid(f(u0+u1))
//
// R6: 178.8 us (priors ~33 us/chunk, route ~9, KCHUNK=8, MALL holds P).
// R6 diagnosis: priors is MLP-latency-bound on cold w global loads (VALUBusy
// ~8%, HBM ~2.3 TB/s << 6.3). R7: DMA-stage each block's 32 KB w tile into
// LDS via global_load_lds width=16 (deep async queue, no VGPR cost), compute
// with IDENTICAL R6 FMA geometry reading w via ds_read_b128. x stays global
// (L2/L3-warm). Route/transpose/fallback unchanged (verified).

#define KK 32
#define BB 32
#define RR 2048
#define CC 16
#define OO 32

__device__ __forceinline__ float sigmoidf_(float v) {
  return 1.0f / (1.0f + __expf(-v));
}

// ---------------- Phase 0: x[B][R][C] -> xT[R][C][B] (once) ----------------
__global__ void __launch_bounds__(256)
transpose_x(const float* __restrict__ x, float* __restrict__ xT) {
  const int r = blockIdx.x;          // 0..2047
  const int t = threadIdx.x;
  const int b = t >> 3;              // 0..31
  const int c = (t & 7) * 2;         // 0,2,..,14
  const float2 v = *(const float2*)(x + ((size_t)b * RR + r) * CC + c);
  xT[((size_t)r * CC + c) * BB + b]     = v.x;
  xT[((size_t)r * CC + c + 1) * BB + b] = v.y;
}

// ---------------- Phase 1: priors einsum (DMA-staged w) ----------------
// grid = KCHUNK*128 x 256 thr. Block = (kl = bid>>7, 16-row tile rt).
// Stage: w tile rows rt*16..+16 (contiguous 32 KB) -> LDS, 8 rounds x
// (256 lanes x 16 B), linear dest (m97 pattern). Compute: R6 geometry —
// lane og=l&3, bg=(l>>2)&3, rq=l>>4; thread tile 8b x 8o, w from LDS.
__global__ void __launch_bounds__(256, 4)
capsule_priors4(const float* __restrict__ xT, const float* __restrict__ w,
                float* __restrict__ P, int k0) {
  __shared__ float wlds[16 * 512];   // 32 KB: [16 rows][512 floats]

  const int bid  = blockIdx.x;
  const int kl   = bid >> 7;
  const int rt   = bid & 127;
  const int t    = threadIdx.x;
  const int lane = t & 63;
  const int wid  = t >> 6;           // 0..3
  const int og   = lane & 3;
  const int bg   = (lane >> 2) & 3;
  const int rq   = lane >> 4;        // 0..3
  const int r16  = wid * 4 + rq;     // row within tile
  const int r    = rt * 16 + r16;
  const int k    = k0 + kl;

  // ---- async DMA: 32 KB w tile -> LDS (linear, 1:1) ----
  const char* wsrc = (const char*)(w + (size_t)k * ((size_t)RR * CC * OO)
                                     + (size_t)rt * (16 * CC * OO));
  #pragma unroll
  for (int i = 0; i < 8; ++i) {
    const int blk = i * 256 + wid * 64;          // float4 index of wave base
    const void* g = wsrc + ((size_t)blk + lane) * 16;
    void* l = (char*)wlds + (size_t)blk * 16;    // wave-uniform base
    __builtin_amdgcn_global_load_lds(
        (const __attribute__((address_space(1))) unsigned int*)g,
        (__attribute__((address_space(3))) unsigned int*)l, 16, 0, 0);
  }
  asm volatile("s_waitcnt vmcnt(0)" ::: "memory");
  __syncthreads();

  const float* __restrict__ xr = xT + ((size_t)r * CC) * BB + bg * 8;
  const float* wrl = wlds + r16 * 512 + og * 8;

  float4 acc[8][2];
  #pragma unroll
  for (int bb = 0; bb < 8; ++bb) {
    acc[bb][0] = make_float4(0.f, 0.f, 0.f, 0.f);
    acc[bb][1] = make_float4(0.f, 0.f, 0.f, 0.f);
  }

  #pragma unroll
  for (int c = 0; c < CC; ++c) {
    const float4 xf0 = *(const float4*)(xr + c * BB);
    const float4 xf1 = *(const float4*)(xr + c * BB + 4);
    const float4 wf0 = *(const float4*)(wrl + c * 32);
    const float4 wf1 = *(const float4*)(wrl + c * 32 + 4);
    const float xs[8] = {xf0.x, xf0.y, xf0.z, xf0.w, xf1.x, xf1.y, xf1.z, xf1.w};
    #pragma unroll
    for (int bb = 0; bb < 8; ++bb) {
      const float s = xs[bb];
      acc[bb][0].x = fmaf(s, wf0.x, acc[bb][0].x);
      acc[bb][0].y = fmaf(s, wf0.y, acc[bb][0].y);
      acc[bb][0].z = fmaf(s, wf0.z, acc[bb][0].z);
      acc[bb][0].w = fmaf(s, wf0.w, acc[bb][0].w);
      acc[bb][1].x = fmaf(s, wf1.x, acc[bb][1].x);
      acc[bb][1].y = fmaf(s, wf1.y, acc[bb][1].y);
      acc[bb][1].z = fmaf(s, wf1.z, acc[bb][1].z);
      acc[bb][1].w = fmaf(s, wf1.w, acc[bb][1].w);
    }
  }

  #pragma unroll
  for (int bb = 0; bb < 8; ++bb) {
    const int b = bg * 8 + bb;
    float* Pd = P + (((size_t)kl * BB + b) * RR + r) * OO + og * 8;
    *(float4*)(Pd)     = acc[bb][0];
    *(float4*)(Pd + 4) = acc[bb][1];
  }
}

// ---------------- Phase 2: routing (unchanged from R3/R4/R6, verified) ----
__global__ void __launch_bounds__(1024, 4)
capsule_route(const float* __restrict__ P, float* __restrict__ out, int k0) {
  __shared__ float swv[512];
  __shared__ float sU[32];
  __shared__ float sM[16];
  __shared__ float sZ[16];

  const int bid  = blockIdx.x;
  const int kl   = bid >> 5;
  const int b    = bid & 31;
  const int t    = threadIdx.x;
  const int o4   = t & 7;
  const int G    = t >> 3;
  const int lane = t & 63;
  const int wid  = t >> 6;

  const float* __restrict__ Pb = P + ((size_t)kl * BB + b) * ((size_t)RR * OO);

  float4 preg[16];
  float4 cs = make_float4(0.f, 0.f, 0.f, 0.f);
  #pragma unroll
  for (int j = 0; j < 16; ++j) {
    preg[j] = *(const float4*)(Pb + (size_t)(j * 128 + G) * OO + (o4 << 2));
    cs.x += preg[j].x; cs.y += preg[j].y; cs.z += preg[j].z; cs.w += preg[j].w;
  }

  #pragma unroll
  for (int m = 8; m <= 32; m <<= 1) {
    cs.x += __shfl_xor(cs.x, m);
    cs.y += __shfl_xor(cs.y, m);
    cs.z += __shfl_xor(cs.z, m);
    cs.w += __shfl_xor(cs.w, m);
  }
  if (lane < 8) *(float4*)&swv[(wid << 5) + (o4 << 2)] = cs;
  __syncthreads();
  if (t < OO) {
    float s = 0.f;
    #pragma unroll
    for (int w2 = 0; w2 < 16; ++w2) s += swv[(w2 << 5) + t];
    sU[t] = sigmoidf_(s * (1.0f / 2048.0f));
  }
  __syncthreads();

  #pragma unroll 1
  for (int pass = 0; pass < 2; ++pass) {
    const float4 v = *(const float4*)&sU[o4 << 2];

    float d[16];
    #pragma unroll
    for (int j = 0; j < 16; ++j) {
      d[j] = preg[j].x * v.x + preg[j].y * v.y + preg[j].z * v.z + preg[j].w * v.w;
    }
    #pragma unroll
    for (int j = 0; j < 16; ++j) {
      d[j] += __shfl_xor(d[j], 1);
      d[j] += __shfl_xor(d[j], 2);
      d[j] += __shfl_xor(d[j], 4);
    }

    float mx = d[0];
    #pragma unroll
    for (int j = 1; j < 16; ++j) mx = fmaxf(mx, d[j]);
    mx = fmaxf(mx, __shfl_xor(mx, 8));
    mx = fmaxf(mx, __shfl_xor(mx, 16));
    mx = fmaxf(mx, __shfl_xor(mx, 32));
    if (lane == 0) sM[wid] = mx;
    __syncthreads();
    float M = sM[0];
    #pragma unroll
    for (int w2 = 1; w2 < 16; ++w2) M = fmaxf(M, sM[w2]);

    float z = 0.f;
    float4 acc = make_float4(0.f, 0.f, 0.f, 0.f);
    #pragma unroll
    for (int j = 0; j < 16; ++j) { d[j] = __expf(d[j] - M); z += d[j]; }
    #pragma unroll
    for (int j = 0; j < 16; ++j) {
      acc.x = fmaf(d[j], preg[j].x, acc.x);
      acc.y = fmaf(d[j], preg[j].y, acc.y);
      acc.z = fmaf(d[j], preg[j].z, acc.z);
      acc.w = fmaf(d[j], preg[j].w, acc.w);
    }
    #pragma unroll
    for (int m = 8; m <= 32; m <<= 1) {
      z     += __shfl_xor(z, m);
      acc.x += __shfl_xor(acc.x, m);
      acc.y += __shfl_xor(acc.y, m);
      acc.z += __shfl_xor(acc.z, m);
      acc.w += __shfl_xor(acc.w, m);
    }
    if (lane < 8) {
      *(float4*)&swv[(wid << 5) + (o4 << 2)] = acc;
      if (o4 == 0) sZ[wid] = z;
    }
    __syncthreads();
    if (t < OO) {
      float zz = 0.f, s = 0.f;
      #pragma unroll
      for (int w2 = 0; w2 < 16; ++w2) { zz += sZ[w2]; s += swv[(w2 << 5) + t]; }
      const float fo = s / zz;
      if (pass == 0) {
        sU[t] += sigmoidf_(fo);
      } else {
        out[((size_t)((k0 + kl) * BB + b)) * OO + t] = sigmoidf_(fo);
      }
    }
    __syncthreads();
  }
}

// ---------------- Fallback: round-1 fused kernel (verified, 226 us) --------
#define THREADS 1024
#define PLDS_FLOATS (1024 * 32)
#define SWV_OFF PLDS_FLOATS
#define SU_OFF (SWV_OFF + 16 * 32)
#define SM_OFF (SU_OFF + 32)
#define SZ_OFF (SM_OFF + 16)
#define SMEM_FLOATS (SZ_OFF + 16)
#define SMEM_BYTES (SMEM_FLOATS * 4)

__global__ void __launch_bounds__(THREADS, 4)
capsule_fused(const float* __restrict__ x, const float* __restrict__ w,
              float* __restrict__ out) {
  extern __shared__ float smem[];
  float* Plds = smem;
  float* swv  = smem + SWV_OFF;
  float* sU   = smem + SU_OFF;
  float* sM   = smem + SM_OFF;
  float* sZ   = smem + SZ_OFF;

  const int t    = threadIdx.x;
  const int o4   = t & 7;
  const int G    = t >> 3;
  const int lane = t & 63;
  const int wid  = t >> 6;
  const int swz  = ((o4 ^ (G & 7)) << 2);

  const int bid  = blockIdx.x;
  const int xcd  = bid & 7;
  const int slot = bid >> 3;
  const int k    = xcd + 8 * (slot >> 5);
  const int b    = slot & 31;

  const float* __restrict__ xb = x + (size_t)b * (RR * CC);
  const float* __restrict__ wk = w + (size_t)k * ((size_t)RR * CC * OO);

  float4 preg[8];
  float4 cs = make_float4(0.f, 0.f, 0.f, 0.f);

  #pragma unroll
  for (int j = 0; j < 16; ++j) {
    const int r = ((j & 8) ? 1024 : 0) + 8 * G + (j & 7);
    const float* xr = xb + r * CC;
    float xs[16];
    *(float4*)&xs[0]  = *(const float4*)(xr + 0);
    *(float4*)&xs[4]  = *(const float4*)(xr + 4);
    *(float4*)&xs[8]  = *(const float4*)(xr + 8);
    *(float4*)&xs[12] = *(const float4*)(xr + 12);
    const float* wr = wk + (size_t)r * (CC * OO) + (o4 << 2);
    float4 a = make_float4(0.f, 0.f, 0.f, 0.f);
    #pragma unroll
    for (int c = 0; c < CC; ++c) {
      const float4 wv = *(const float4*)(wr + c * OO);
      a.x = fmaf(xs[c], wv.x, a.x);
      a.y = fmaf(xs[c], wv.y, a.y);
      a.z = fmaf(xs[c], wv.z, a.z);
      a.w = fmaf(xs[c], wv.w, a.w);
    }
    if (j < 8) {
      *(float4*)&Plds[((8 * G + (j & 7)) << 5) + swz] = a;
    } else {
      preg[j - 8] = a;
    }
    cs.x += a.x; cs.y += a.y; cs.z += a.z; cs.w += a.w;
  }

  #pragma unroll
  for (int m = 8; m <= 32; m <<= 1) {
    cs.x += __shfl_xor(cs.x, m);
    cs.y += __shfl_xor(cs.y, m);
    cs.z += __shfl_xor(cs.z, m);
    cs.w += __shfl_xor(cs.w, m);
  }
  if (lane < 8) *(float4*)&swv[(wid << 5) + (o4 << 2)] = cs;
  __syncthreads();
  if (t < OO) {
    float s = 0.f;
    #pragma unroll
    for (int w2 = 0; w2 < 16; ++w2) s += swv[(w2 << 5) + t];
    sU[t] = sigmoidf_(s * (1.0f / 2048.0f));
  }
  __syncthreads();

  #pragma unroll 1
  for (int pass = 0; pass < 2; ++pass) {
    const float4 v = *(const float4*)&sU[o4 << 2];
    float d[16];
    #pragma unroll
    for (int j = 0; j < 8; ++j) {
      const float4 p = *(const float4*)&Plds[((8 * G + j) << 5) + swz];
      d[j] = p.x * v.x + p.y * v.y + p.z * v.z + p.w * v.w;
    }
    #pragma unroll
    for (int j = 0; j < 8; ++j) {
      const float4 p = preg[j];
      d[8 + j] = p.x * v.x + p.y * v.y + p.z * v.z + p.w * v.w;
    }
    #pragma unroll
    for (int j = 0; j < 16; ++j) {
      d[j] += __shfl_xor(d[j], 1);
      d[j] += __shfl_xor(d[j], 2);
      d[j] += __shfl_xor(d[j], 4);
    }
    float mx = d[0];
    #pragma unroll
    for (int j = 1; j < 16; ++j) mx = fmaxf(mx, d[j]);
    mx = fmaxf(mx, __shfl_xor(mx, 8));
    mx = fmaxf(mx, __shfl_xor(mx, 16));
    mx = fmaxf(mx, __shfl_xor(mx, 32));
    if (lane == 0) sM[wid] = mx;
    __syncthreads();
    float M = sM[0];
    #pragma unroll
    for (int w2 = 1; w2 < 16; ++w2) M = fmaxf(M, sM[w2]);

    float z = 0.f;
    float4 acc = make_float4(0.f, 0.f, 0.f, 0.f);
    #pragma unroll
    for (int j = 0; j < 16; ++j) { d[j] = __expf(d[j] - M); z += d[j]; }
    #pragma unroll
    for (int j = 0; j < 8; ++j) {
      const float4 p = *(const float4*)&Plds[((8 * G + j) << 5) + swz];
      acc.x = fmaf(d[j], p.x, acc.x);
      acc.y = fmaf(d[j], p.y, acc.y);
      acc.z = fmaf(d[j], p.z, acc.z);
      acc.w = fmaf(d[j], p.w, acc.w);
    }
    #pragma unroll
    for (int j = 0; j < 8; ++j) {
      const float4 p = preg[j];
      acc.x = fmaf(d[8 + j], p.x, acc.x);
      acc.y = fmaf(d[8 + j], p.y, acc.y);
      acc.z = fmaf(d[8 + j], p.z, acc.z);
      acc.w = fmaf(d[8 + j], p.w, acc.w);
    }
    #pragma unroll
    for (int m = 8; m <= 32; m <<= 1) {
      z     += __shfl_xor(z, m);
      acc.x += __shfl_xor(acc.x, m);
      acc.y += __shfl_xor(acc.y, m);
      acc.z += __shfl_xor(acc.z, m);
      acc.w += __shfl_xor(acc.w, m);
    }
    if (lane < 8) {
      *(float4*)&swv[(wid << 5) + (o4 << 2)] = acc;
      if (o4 == 0) sZ[wid] = z;
    }
    __syncthreads();
    if (t < OO) {
      float zz = 0.f, s = 0.f;
      #pragma unroll
      for (int w2 = 0; w2 < 16; ++w2) { zz += sZ[w2]; s += swv[(w2 << 5) + t]; }
      const float fo = s / zz;
      if (pass == 0) {
        sU[t] = sU[t] + sigmoidf_(fo);
      } else {
        out[((k << 5) + b) * OO + t] = sigmoidf_(fo);
      }
    }
    __syncthreads();
  }
}

extern "C" void kernel_launch(void* const* d_in, const int* in_sizes, int n_in,
                              void* d_out, int out_size, void* d_ws, size_t ws_size,
                              hipStream_t stream) {
  const float* x = (const float*)d_in[0];
  const float* w = (const float*)d_in[1];
  float* out = (float*)d_out;
  (void)in_sizes; (void)n_in; (void)out_size;

  const size_t perK = (size_t)BB * RR * OO * sizeof(float);  // 8 MB per k
  const size_t xTsz = (size_t)BB * RR * CC * sizeof(float);  // 4 MB
  int KCHUNK = 0;
  if      (ws_size >= 8 * perK + xTsz) KCHUNK = 8;   // 68 MB working set << MALL
  else if (ws_size >= 4 * perK + xTsz) KCHUNK = 4;

  if (KCHUNK == 0) {
    hipFuncSetAttribute(reinterpret_cast<const void*>(capsule_fused),
                        hipFuncAttributeMaxDynamicSharedMemorySize, SMEM_BYTES);
    capsule_fused<<<dim3(KK * BB), dim3(THREADS), SMEM_BYTES, stream>>>(x, w, out);
    return;
  }

  float* P  = (float*)d_ws;
  float* xT = (float*)((char*)d_ws + KCHUNK * perK);

  transpose_x<<<dim3(RR), dim3(256), 0, stream>>>(x, xT);
  for (int k0 = 0; k0 < KK; k0 += KCHUNK) {
    capsule_priors4<<<dim3(KCHUNK * 128), dim3(256), 0, stream>>>(xT, w, P, k0);
    capsule_route<<<dim3(KCHUNK * 32), dim3(1024), 0, stream>>>(P, out, k0);
  }
}

// Round 8
// 482.327 us; speedup vs baseline: 1.0565x; 1.0565x over previous
//
#include <hip/hip_runtime.h>

// CapsuleLayer dynamic routing — two-phase, fp32-exact.
//   P[k,b,r,o] = sum_c x[b,r,c] * w[k,r,c,o]   (K=B=32, R=2048, C=16, O=32)
//   u0 = sigmoid(colsum(P)/R); f(v) = P^T softmax(P v)
//   u1 = sigmoid(f(u0)); out = sigmoid(f(u0+u1))
//
// R7 post-mortem: global_load_lds amplified HBM fetch 4-5x (172 MB vs 36 MB
// unique) — per-lane LDS-direct requests don't line-coalesce; fatal for the
// single-use w stream. R8: reg-staged w->LDS (8 back-to-back dwordx4/thread
// through the normal coalescing path, 8 KB in flight/wave), then the exact
// R6 FMA geometry reading w from LDS. Route/transpose/fallback unchanged.

#define KK 32
#define BB 32
#define RR 2048
#define CC 16
#define OO 32

__device__ __forceinline__ float sigmoidf_(float v) {
  return 1.0f / (1.0f + __expf(-v));
}

// ---------------- Phase 0: x[B][R][C] -> xT[R][C][B] (once) ----------------
__global__ void __launch_bounds__(256)
transpose_x(const float* __restrict__ x, float* __restrict__ xT) {
  const int r = blockIdx.x;          // 0..2047
  const int t = threadIdx.x;
  const int b = t >> 3;              // 0..31
  const int c = (t & 7) * 2;         // 0,2,..,14
  const float2 v = *(const float2*)(x + ((size_t)b * RR + r) * CC + c);
  xT[((size_t)r * CC + c) * BB + b]     = v.x;
  xT[((size_t)r * CC + c + 1) * BB + b] = v.y;
}

// ---------------- Phase 1: priors einsum (reg-staged w in LDS) -------------
// grid = KCHUNK*128 x 256 thr. Block = (kl = bid>>7, 16-row tile rt).
// Stage: 32 KB w tile -> regs (8 x dwordx4, coalesced) -> LDS. Compute: R6
// geometry — lane og=l&3, bg=(l>>2)&3, rq=l>>4; thread tile 8b x 8o; w from
// LDS [16r][512], x from L2-warm xT[R][C][B].
__global__ void __launch_bounds__(256, 4)
capsule_priors5(const float* __restrict__ xT, const float* __restrict__ w,
                float* __restrict__ P, int k0) {
  __shared__ float wlds[16 * 512];   // 32 KB

  const int bid  = blockIdx.x;
  const int kl   = bid >> 7;
  const int rt   = bid & 127;
  const int t    = threadIdx.x;
  const int lane = t & 63;
  const int og   = lane & 3;
  const int bg   = (lane >> 2) & 3;
  const int rq   = lane >> 4;        // 0..3
  const int wid  = t >> 6;           // 0..3
  const int r16  = wid * 4 + rq;
  const int r    = rt * 16 + r16;
  const int k    = k0 + kl;

  // ---- stage: 8 coalesced float4 loads per thread, then LDS writes ----
  {
    const float4* wsrc = (const float4*)(w + (size_t)k * ((size_t)RR * CC * OO)
                                           + (size_t)rt * (16 * CC * OO));
    float4 v[8];
    #pragma unroll
    for (int i = 0; i < 8; ++i) v[i] = wsrc[i * 256 + t];
    float4* wl = (float4*)wlds;
    #pragma unroll
    for (int i = 0; i < 8; ++i) wl[i * 256 + t] = v[i];
  }
  __syncthreads();

  const float* __restrict__ xr = xT + ((size_t)r * CC) * BB + bg * 8;
  const float* wrl = wlds + r16 * 512 + og * 8;

  float4 acc[8][2];
  #pragma unroll
  for (int bb = 0; bb < 8; ++bb) {
    acc[bb][0] = make_float4(0.f, 0.f, 0.f, 0.f);
    acc[bb][1] = make_float4(0.f, 0.f, 0.f, 0.f);
  }

  #pragma unroll
  for (int c = 0; c < CC; ++c) {
    const float4 xf0 = *(const float4*)(xr + c * BB);
    const float4 xf1 = *(const float4*)(xr + c * BB + 4);
    const float4 wf0 = *(const float4*)(wrl + c * 32);
    const float4 wf1 = *(const float4*)(wrl + c * 32 + 4);
    const float xs[8] = {xf0.x, xf0.y, xf0.z, xf0.w, xf1.x, xf1.y, xf1.z, xf1.w};
    #pragma unroll
    for (int bb = 0; bb < 8; ++bb) {
      const float s = xs[bb];
      acc[bb][0].x = fmaf(s, wf0.x, acc[bb][0].x);
      acc[bb][0].y = fmaf(s, wf0.y, acc[bb][0].y);
      acc[bb][0].z = fmaf(s, wf0.z, acc[bb][0].z);
      acc[bb][0].w = fmaf(s, wf0.w, acc[bb][0].w);
      acc[bb][1].x = fmaf(s, wf1.x, acc[bb][1].x);
      acc[bb][1].y = fmaf(s, wf1.y, acc[bb][1].y);
      acc[bb][1].z = fmaf(s, wf1.z, acc[bb][1].z);
      acc[bb][1].w = fmaf(s, wf1.w, acc[bb][1].w);
    }
  }

  #pragma unroll
  for (int bb = 0; bb < 8; ++bb) {
    const int b = bg * 8 + bb;
    float* Pd = P + (((size_t)kl * BB + b) * RR + r) * OO + og * 8;
    *(float4*)(Pd)     = acc[bb][0];
    *(float4*)(Pd + 4) = acc[bb][1];
  }
}

// ---------------- Phase 2: routing (unchanged from R3/R4/R6, verified) ----
__global__ void __launch_bounds__(1024, 4)
capsule_route(const float* __restrict__ P, float* __restrict__ out, int k0) {
  __shared__ float swv[512];
  __shared__ float sU[32];
  __shared__ float sM[16];
  __shared__ float sZ[16];

  const int bid  = blockIdx.x;
  const int kl   = bid >> 5;
  const int b    = bid & 31;
  const int t    = threadIdx.x;
  const int o4   = t & 7;
  const int G    = t >> 3;
  const int lane = t & 63;
  const int wid  = t >> 6;

  const float* __restrict__ Pb = P + ((size_t)kl * BB + b) * ((size_t)RR * OO);

  float4 preg[16];
  float4 cs = make_float4(0.f, 0.f, 0.f, 0.f);
  #pragma unroll
  for (int j = 0; j < 16; ++j) {
    preg[j] = *(const float4*)(Pb + (size_t)(j * 128 + G) * OO + (o4 << 2));
    cs.x += preg[j].x; cs.y += preg[j].y; cs.z += preg[j].z; cs.w += preg[j].w;
  }

  #pragma unroll
  for (int m = 8; m <= 32; m <<= 1) {
    cs.x += __shfl_xor(cs.x, m);
    cs.y += __shfl_xor(cs.y, m);
    cs.z += __shfl_xor(cs.z, m);
    cs.w += __shfl_xor(cs.w, m);
  }
  if (lane < 8) *(float4*)&swv[(wid << 5) + (o4 << 2)] = cs;
  __syncthreads();
  if (t < OO) {
    float s = 0.f;
    #pragma unroll
    for (int w2 = 0; w2 < 16; ++w2) s += swv[(w2 << 5) + t];
    sU[t] = sigmoidf_(s * (1.0f / 2048.0f));
  }
  __syncthreads();

  #pragma unroll 1
  for (int pass = 0; pass < 2; ++pass) {
    const float4 v = *(const float4*)&sU[o4 << 2];

    float d[16];
    #pragma unroll
    for (int j = 0; j < 16; ++j) {
      d[j] = preg[j].x * v.x + preg[j].y * v.y + preg[j].z * v.z + preg[j].w * v.w;
    }
    #pragma unroll
    for (int j = 0; j < 16; ++j) {
      d[j] += __shfl_xor(d[j], 1);
      d[j] += __shfl_xor(d[j], 2);
      d[j] += __shfl_xor(d[j], 4);
    }

    float mx = d[0];
    #pragma unroll
    for (int j = 1; j < 16; ++j) mx = fmaxf(mx, d[j]);
    mx = fmaxf(mx, __shfl_xor(mx, 8));
    mx = fmaxf(mx, __shfl_xor(mx, 16));
    mx = fmaxf(mx, __shfl_xor(mx, 32));
    if (lane == 0) sM[wid] = mx;
    __syncthreads();
    float M = sM[0];
    #pragma unroll
    for (int w2 = 1; w2 < 16; ++w2) M = fmaxf(M, sM[w2]);

    float z = 0.f;
    float4 acc = make_float4(0.f, 0.f, 0.f, 0.f);
    #pragma unroll
    for (int j = 0; j < 16; ++j) { d[j] = __expf(d[j] - M); z += d[j]; }
    #pragma unroll
    for (int j = 0; j < 16; ++j) {
      acc.x = fmaf(d[j], preg[j].x, acc.x);
      acc.y = fmaf(d[j], preg[j].y, acc.y);
      acc.z = fmaf(d[j], preg[j].z, acc.z);
      acc.w = fmaf(d[j], preg[j].w, acc.w);
    }
    #pragma unroll
    for (int m = 8; m <= 32; m <<= 1) {
      z     += __shfl_xor(z, m);
      acc.x += __shfl_xor(acc.x, m);
      acc.y += __shfl_xor(acc.y, m);
      acc.z += __shfl_xor(acc.z, m);
      acc.w += __shfl_xor(acc.w, m);
    }
    if (lane < 8) {
      *(float4*)&swv[(wid << 5) + (o4 << 2)] = acc;
      if (o4 == 0) sZ[wid] = z;
    }
    __syncthreads();
    if (t < OO) {
      float zz = 0.f, s = 0.f;
      #pragma unroll
      for (int w2 = 0; w2 < 16; ++w2) { zz += sZ[w2]; s += swv[(w2 << 5) + t]; }
      const float fo = s / zz;
      if (pass == 0) {
        sU[t] += sigmoidf_(fo);
      } else {
        out[((size_t)((k0 + kl) * BB + b)) * OO + t] = sigmoidf_(fo);
      }
    }
    __syncthreads();
  }
}

// ---------------- Fallback: round-1 fused kernel (verified, 226 us) --------
#define THREADS 1024
#define PLDS_FLOATS (1024 * 32)
#define SWV_OFF PLDS_FLOATS
#define SU_OFF (SWV_OFF + 16 * 32)
#define SM_OFF (SU_OFF + 32)
#define SZ_OFF (SM_OFF + 16)
#define SMEM_FLOATS (SZ_OFF + 16)
#define SMEM_BYTES (SMEM_FLOATS * 4)

__global__ void __launch_bounds__(THREADS, 4)
capsule_fused(const float* __restrict__ x, const float* __restrict__ w,
              float* __restrict__ out) {
  extern __shared__ float smem[];
  float* Plds = smem;
  float* swv  = smem + SWV_OFF;
  float* sU   = smem + SU_OFF;
  float* sM   = smem + SM_OFF;
  float* sZ   = smem + SZ_OFF;

  const int t    = threadIdx.x;
  const int o4   = t & 7;
  const int G    = t >> 3;
  const int lane = t & 63;
  const int wid  = t >> 6;
  const int swz  = ((o4 ^ (G & 7)) << 2);

  const int bid  = blockIdx.x;
  const int xcd  = bid & 7;
  const int slot = bid >> 3;
  const int k    = xcd + 8 * (slot >> 5);
  const int b    = slot & 31;

  const float* __restrict__ xb = x + (size_t)b * (RR * CC);
  const float* __restrict__ wk = w + (size_t)k * ((size_t)RR * CC * OO);

  float4 preg[8];
  float4 cs = make_float4(0.f, 0.f, 0.f, 0.f);

  #pragma unroll
  for (int j = 0; j < 16; ++j) {
    const int r = ((j & 8) ? 1024 : 0) + 8 * G + (j & 7);
    const float* xr = xb + r * CC;
    float xs[16];
    *(float4*)&xs[0]  = *(const float4*)(xr + 0);
    *(float4*)&xs[4]  = *(const float4*)(xr + 4);
    *(float4*)&xs[8]  = *(const float4*)(xr + 8);
    *(float4*)&xs[12] = *(const float4*)(xr + 12);
    const float* wr = wk + (size_t)r * (CC * OO) + (o4 << 2);
    float4 a = make_float4(0.f, 0.f, 0.f, 0.f);
    #pragma unroll
    for (int c = 0; c < CC; ++c) {
      const float4 wv = *(const float4*)(wr + c * OO);
      a.x = fmaf(xs[c], wv.x, a.x);
      a.y = fmaf(xs[c], wv.y, a.y);
      a.z = fmaf(xs[c], wv.z, a.z);
      a.w = fmaf(xs[c], wv.w, a.w);
    }
    if (j < 8) {
      *(float4*)&Plds[((8 * G + (j & 7)) << 5) + swz] = a;
    } else {
      preg[j - 8] = a;
    }
    cs.x += a.x; cs.y += a.y; cs.z += a.z; cs.w += a.w;
  }

  #pragma unroll
  for (int m = 8; m <= 32; m <<= 1) {
    cs.x += __shfl_xor(cs.x, m);
    cs.y += __shfl_xor(cs.y, m);
    cs.z += __shfl_xor(cs.z, m);
    cs.w += __shfl_xor(cs.w, m);
  }
  if (lane < 8) *(float4*)&swv[(wid << 5) + (o4 << 2)] = cs;
  __syncthreads();
  if (t < OO) {
    float s = 0.f;
    #pragma unroll
    for (int w2 = 0; w2 < 16; ++w2) s += swv[(w2 << 5) + t];
    sU[t] = sigmoidf_(s * (1.0f / 2048.0f));
  }
  __syncthreads();

  #pragma unroll 1
  for (int pass = 0; pass < 2; ++pass) {
    const float4 v = *(const float4*)&sU[o4 << 2];
    float d[16];
    #pragma unroll
    for (int j = 0; j < 8; ++j) {
      const float4 p = *(const float4*)&Plds[((8 * G + j) << 5) + swz];
      d[j] = p.x * v.x + p.y * v.y + p.z * v.z + p.w * v.w;
    }
    #pragma unroll
    for (int j = 0; j < 8; ++j) {
      const float4 p = preg[j];
      d[8 + j] = p.x * v.x + p.y * v.y + p.z * v.z + p.w * v.w;
    }
    #pragma unroll
    for (int j = 0; j < 16; ++j) {
      d[j] += __shfl_xor(d[j], 1);
      d[j] += __shfl_xor(d[j], 2);
      d[j] += __shfl_xor(d[j], 4);
    }
    float mx = d[0];
    #pragma unroll
    for (int j = 1; j < 16; ++j) mx = fmaxf(mx, d[j]);
    mx = fmaxf(mx, __shfl_xor(mx, 8));
    mx = fmaxf(mx, __shfl_xor(mx, 16));
    mx = fmaxf(mx, __shfl_xor(mx, 32));
    if (lane == 0) sM[wid] = mx;
    __syncthreads();
    float M = sM[0];
    #pragma unroll
    for (int w2 = 1; w2 < 16; ++w2) M = fmaxf(M, sM[w2]);

    float z = 0.f;
    float4 acc = make_float4(0.f, 0.f, 0.f, 0.f);
    #pragma unroll
    for (int j = 0; j < 16; ++j) { d[j] = __expf(d[j] - M); z += d[j]; }
    #pragma unroll
    for (int j = 0; j < 8; ++j) {
      const float4 p = *(const float4*)&Plds[((8 * G + j) << 5) + swz];
      acc.x = fmaf(d[j], p.x, acc.x);
      acc.y = fmaf(d[j], p.y, acc.y);
      acc.z = fmaf(d[j], p.z, acc.z);
      acc.w = fmaf(d[j], p.w, acc.w);
    }
    #pragma unroll
    for (int j = 0; j < 8; ++j) {
      const float4 p = preg[j];
      acc.x = fmaf(d[8 + j], p.x, acc.x);
      acc.y = fmaf(d[8 + j], p.y, acc.y);
      acc.z = fmaf(d[8 + j], p.z, acc.z);
      acc.w = fmaf(d[8 + j], p.w, acc.w);
    }
    #pragma unroll
    for (int m = 8; m <= 32; m <<= 1) {
      z     += __shfl_xor(z, m);
      acc.x += __shfl_xor(acc.x, m);
      acc.y += __shfl_xor(acc.y, m);
      acc.z += __shfl_xor(acc.z, m);
      acc.w += __shfl_xor(acc.w, m);
    }
    if (lane < 8) {
      *(float4*)&swv[(wid << 5) + (o4 << 2)] = acc;
      if (o4 == 0) sZ[wid] = z;
    }
    __syncthreads();
    if (t < OO) {
      float zz = 0.f, s = 0.f;
      #pragma unroll
      for (int w2 = 0; w2 < 16; ++w2) { zz += sZ[w2]; s += swv[(w2 << 5) + t]; }
      const float fo = s / zz;
      if (pass == 0) {
        sU[t] = sU[t] + sigmoidf_(fo);
      } else {
        out[((k << 5) + b) * OO + t] = sigmoidf_(fo);
      }
    }
    __syncthreads();
  }
}

extern "C" void kernel_launch(void* const* d_in, const int* in_sizes, int n_in,
                              void* d_out, int out_size, void* d_ws, size_t ws_size,
                              hipStream_t stream) {
  const float* x = (const float*)d_in[0];
  const float* w = (const float*)d_in[1];
  float* out = (float*)d_out;
  (void)in_sizes; (void)n_in; (void)out_size;

  const size_t perK = (size_t)BB * RR * OO * sizeof(float);  // 8 MB per k
  const size_t xTsz = (size_t)BB * RR * CC * sizeof(float);  // 4 MB
  int KCHUNK = 0;
  if      (ws_size >= 8 * perK + xTsz) KCHUNK = 8;   // 68 MB working set << MALL
  else if (ws_size >= 4 * perK + xTsz) KCHUNK = 4;

  if (KCHUNK == 0) {
    hipFuncSetAttribute(reinterpret_cast<const void*>(capsule_fused),
                        hipFuncAttributeMaxDynamicSharedMemorySize, SMEM_BYTES);
    capsule_fused<<<dim3(KK * BB), dim3(THREADS), SMEM_BYTES, stream>>>(x, w, out);
    return;
  }

  float* P  = (float*)d_ws;
  float* xT = (float*)((char*)d_ws + KCHUNK * perK);

  transpose_x<<<dim3(RR), dim3(256), 0, stream>>>(x, xT);
  for (int k0 = 0; k0 < KK; k0 += KCHUNK) {
    capsule_priors5<<<dim3(KCHUNK * 128), dim3(256), 0, stream>>>(xT, w, P, k0);
    capsule_route<<<dim3(KCHUNK * 32), dim3(1024), 0, stream>>>(P, out, k0);
  }
}